// Round 7
// baseline (777.025 us; speedup 1.0000x reference)
//
#include <hip/hip_runtime.h>
#include <hip/hip_cooperative_groups.h>
#include <math.h>

namespace cg = cooperative_groups;

// ProGAT: B=8,S=512,NB=23,INIT=512,E=256,R=3,T=2
// R7: single cooperative mega-kernel (grid.sync between phases) to kill
// the ~10us/dispatch serialization cost. Phase bodies = R6 kernels.

#define BSZ   8
#define SEQ   512
#define NBR   23
#define EMB   256
#define INITD 512
#define BS    (BSZ*SEQ)     // 4096
#define G3    (3*EMB)       // 768
#define NEGV  -9e8f

typedef __attribute__((ext_vector_type(8))) short short8;
typedef __attribute__((ext_vector_type(4))) float f32x4;

__device__ __forceinline__ float lrelu(float x){ return x > 0.f ? x : 0.01f*x; }
__device__ __forceinline__ float elu1 (float x){ return x > 0.f ? x : (expf(x)-1.f); }
__device__ __forceinline__ float sigm (float x){ return 1.f/(1.f+expf(-x)); }
__device__ __forceinline__ float bf2f(ushort u){
    union { unsigned int i; float f; } v; v.i = ((unsigned int)u) << 16; return v.f;
}
__device__ __forceinline__ ushort f2bf(float f){
    union { float f; unsigned int i; } v; v.f = f;
    unsigned int u = v.i;
    return (ushort)((u + 0x7FFFu + ((u >> 16) & 1u)) >> 16);   // RNE
}

__device__ __forceinline__ void gload_lds16(const void* g, void* l) {
    __builtin_amdgcn_global_load_lds(
        (const __attribute__((address_space(1))) unsigned int*)g,
        (__attribute__((address_space(3))) unsigned int*)l,
        16, 0, 0);
}

template<int BN> struct GemmLdsT {
    ushort A[2][128][64];
    ushort B[2][BN][64];
};

union MegaLds {
    GemmLdsT<128> g;                                      // 64 KiB
    struct { float w_s[SEQ]; float red[256]; } pv;
    struct { float xs[EMB]; float hs[EMB]; float gis[192]; float ghs[192]; } st;
    float red256[256];
};

// ---- fp32 -> bf16 converter, 9 segments (blockIdx.y = seg); separate dispatch
__global__ __launch_bounds__(256) void convert9_kernel(
    const float* s0, ushort* d0, int n0,
    const float* s1, ushort* d1, int n1,
    const float* s2, ushort* d2, int n2,
    const float* s3, ushort* d3, int n3,
    const float* s4, ushort* d4, int n4,
    const float* s5, ushort* d5, int n5,
    const float* s6, ushort* d6, int n6,
    const float* s7, ushort* d7, int n7,
    const float* s8, ushort* d8, int n8)
{
    const float* srcs[9] = {s0,s1,s2,s3,s4,s5,s6,s7,s8};
    ushort* dsts[9] = {d0,d1,d2,d3,d4,d5,d6,d7,d8};
    int ns[9] = {n0,n1,n2,n3,n4,n5,n6,n7,n8};
    int seg = blockIdx.y;
    const float* s = srcs[seg]; ushort* d = dsts[seg]; int n = ns[seg];
    size_t i = ((size_t)blockIdx.x * 256 + threadIdx.x) * 8;
    size_t stride = (size_t)gridDim.x * 256 * 8;
    for (; i < (size_t)n; i += stride) {
        float4 a = *reinterpret_cast<const float4*>(s + i);
        float4 b = *reinterpret_cast<const float4*>(s + i + 4);
        uint4 o;
        o.x = (unsigned)f2bf(a.x) | ((unsigned)f2bf(a.y) << 16);
        o.y = (unsigned)f2bf(a.z) | ((unsigned)f2bf(a.w) << 16);
        o.z = (unsigned)f2bf(b.x) | ((unsigned)f2bf(b.y) << 16);
        o.w = (unsigned)f2bf(b.z) | ((unsigned)f2bf(b.w) << 16);
        *reinterpret_cast<uint4*>(d + i) = o;
    }
}

// ---- C = act(A @ W^T + bias); MFMA 16x16x32 bf16, 128xBN tile, BK=64,
// global_load_lds staging (linear dest, inverse-swizzled source), dbuf.
template<int BN, int ACT, bool WF32, bool WBF>
__device__ __forceinline__ void gemm_dev(
    const ushort* __restrict__ A, const ushort* __restrict__ W,
    const float* __restrict__ bias,
    float* __restrict__ C, ushort* __restrict__ Cbf,
    int N, int K, int bx, int by, GemmLdsT<BN>& L)
{
    constexpr int FN = BN / 32;
    const int tid = threadIdx.x;
    const int m0 = bx * 128, n0 = by * BN;
    const int wv = tid >> 6, lane = tid & 63;
    const int fr = lane & 15, grp = lane >> 4;
    const int kc = K >> 3;
    const int mh = wv & 1, nh = wv >> 1;
    const int lrow = lane >> 3;
    const int csrc = (lane & 7) ^ lrow;

    f32x4 acc[4][FN];
    #pragma unroll
    for (int i = 0; i < 4; ++i)
        #pragma unroll
        for (int n = 0; n < FN; ++n) acc[i][n] = (f32x4){0.f,0.f,0.f,0.f};

    auto stage = [&](int c, int k0) {
        const int kch = (k0 >> 3) + csrc;
        #pragma unroll
        for (int i = 0; i < 4; ++i) {
            const int s = (wv << 2) + i;
            const ushort* g = A + ((size_t)(m0 + (s << 3) + lrow) * kc + kch) * 8;
            gload_lds16(g, &L.A[c][s << 3][0]);
        }
        #pragma unroll
        for (int i = 0; i < FN; ++i) {
            const int s = wv * FN + i;
            const ushort* g = W + ((size_t)(n0 + (s << 3) + lrow) * kc + kch) * 8;
            gload_lds16(g, &L.B[c][s << 3][0]);
        }
    };

    auto compute = [&](int c) {
        #pragma unroll
        for (int ks = 0; ks < 2; ++ks) {
            short8 af[4];
            #pragma unroll
            for (int i = 0; i < 4; ++i) {
                const int ar = (mh << 6) + (i << 4) + fr;
                af[i] = *reinterpret_cast<const short8*>(
                    &L.A[c][ar][(((ks << 2) + grp) ^ (ar & 7)) << 3]);
            }
            #pragma unroll
            for (int n = 0; n < FN; ++n) {
                const int br = nh * (BN/2) + (n << 4) + fr;
                short8 bv = *reinterpret_cast<const short8*>(
                    &L.B[c][br][(((ks << 2) + grp) ^ (br & 7)) << 3]);
                #pragma unroll
                for (int i = 0; i < 4; ++i)
                    acc[i][n] = __builtin_amdgcn_mfma_f32_16x16x32_bf16(
                        af[i], bv, acc[i][n], 0, 0, 0);
            }
        }
    };

    const int KT = K >> 6;
    stage(0, 0);
    __syncthreads();
    int cur = 0;
    for (int kt = 1; kt < KT; ++kt) {
        stage(cur ^ 1, kt << 6);
        compute(cur);
        __syncthreads();
        cur ^= 1;
    }
    compute(cur);

    // D layout (m89): col = lane&15, row = (lane>>4)*4 + j
    #pragma unroll
    for (int i = 0; i < 4; ++i) {
        const int mrow = m0 + (mh << 6) + (i << 4) + (grp << 2);
        #pragma unroll
        for (int n = 0; n < FN; ++n) {
            const int col = n0 + nh * (BN/2) + (n << 4) + fr;
            const float bv = bias[col];
            #pragma unroll
            for (int j = 0; j < 4; ++j) {
                float t = acc[i][n][j] + bv;
                if (ACT == 1) t = lrelu(t);
                size_t off = (size_t)(mrow + j) * N + col;
                if (WF32) C[off] = t;
                if (WBF)  Cbf[off] = f2bf(t);
            }
        }
    }
}

// dot2: 32 rows per vb (4 waves x 8 rows)
__device__ __forceinline__ void dot2_body(
    int b, const float* __restrict__ center, const float* __restrict__ nbrbase,
    const float* __restrict__ alignWd, float* __restrict__ cdot, float* __restrict__ ndot)
{
    const int lane = threadIdx.x & 63;
    const int wv   = threadIdx.x >> 6;
    const int e    = lane << 2;
    const int rb   = b * 32 + wv * 8;
    float4 w0 = *reinterpret_cast<const float4*>(&alignWd[e]);
    float4 w1 = *reinterpret_cast<const float4*>(&alignWd[EMB + e]);
    #pragma unroll
    for (int i = 0; i < 8; ++i) {
        const int r = rb + i;
        float4 xc = *reinterpret_cast<const float4*>(&center[(size_t)r*EMB + e]);
        float4 xn = *reinterpret_cast<const float4*>(&nbrbase[(size_t)r*EMB + e]);
        float ac = xc.x*w0.x + xc.y*w0.y + xc.z*w0.z + xc.w*w0.w;
        float an = xn.x*w1.x + xn.y*w1.y + xn.z*w1.z + xn.w*w1.w;
        #pragma unroll
        for (int off = 32; off; off >>= 1) {
            ac += __shfl_xor(ac, off, 64);
            an += __shfl_xor(an, off, 64);
        }
        if (lane == 0) { cdot[r] = ac; ndot[r] = an; }
    }
}

// attn: 8 rows per vb (4 waves x 2 rows)
__device__ __forceinline__ void attn_body(
    int vb, const float* __restrict__ cdot, const float* __restrict__ ndot,
    const int* __restrict__ idx, const ushort* __restrict__ nt,
    float alignBd, ushort* __restrict__ ctxbf)
{
    const int lane = threadIdx.x & 63;
    const int wv   = threadIdx.x >> 6;
    #pragma unroll
    for (int it = 0; it < 2; ++it) {
        const int r = vb*8 + wv*2 + it;
        const int b = r >> 9;
        float sc = -3e38f, vm = 0.f; int row = 0;
        if (lane < NBR) {
            int j = idx[(size_t)r*NBR + lane];
            int valid = (j >= 0);
            int jj = valid ? j : j + SEQ;   // JAX wrap: f[-1] = last row
            row = b*SEQ + jj;
            vm = (float)valid;
            sc = lrelu(cdot[r] + ndot[row] + alignBd) + (valid ? 0.f : NEGV);
        }
        float m = sc;
        #pragma unroll
        for (int off = 32; off; off >>= 1) m = fmaxf(m, __shfl_xor(m, off, 64));
        float ev = (lane < NBR) ? expf(sc - m) : 0.f;
        float s = ev;
        #pragma unroll
        for (int off = 32; off; off >>= 1) s += __shfl_xor(s, off, 64);
        float wgt = ev * vm / s;
        float acc0 = 0.f, acc1 = 0.f, acc2 = 0.f, acc3 = 0.f;
        const int e = lane << 2;
        #pragma unroll 1
        for (int n = 0; n < NBR; ++n) {
            float wn = __shfl(wgt, n, 64);
            int   rn = __shfl(row, n, 64);
            ushort4 v = *reinterpret_cast<const ushort4*>(&nt[(size_t)rn*EMB + e]);
            acc0 += wn * bf2f(v.x); acc1 += wn * bf2f(v.y);
            acc2 += wn * bf2f(v.z); acc3 += wn * bf2f(v.w);
        }
        uint2 o;
        o.x = (unsigned)f2bf(elu1(acc0)) | ((unsigned)f2bf(elu1(acc1)) << 16);
        o.y = (unsigned)f2bf(elu1(acc2)) | ((unsigned)f2bf(elu1(acc3)) << 16);
        *reinterpret_cast<uint2*>(&ctxbf[(size_t)r*EMB + e]) = o;
    }
}

// gru: 8 rows per vb (4 waves x 2 rows)
__device__ __forceinline__ void gru_body(
    int vb, const ushort* __restrict__ gibf, const ushort* __restrict__ ghbf,
    const float* __restrict__ hprev,
    float* __restrict__ hout, ushort* __restrict__ hbf,
    float* __restrict__ actout, ushort* __restrict__ actbf)
{
    #pragma unroll
    for (int it = 0; it < 2; ++it) {
        const size_t r = (size_t)vb*8 + it*4 + (threadIdx.x >> 6);
        const int    e = (threadIdx.x & 63) << 2;
        const size_t gb = r*G3 + e, hb = r*EMB + e;
        ushort4 ir4 = *reinterpret_cast<const ushort4*>(&gibf[gb]);
        ushort4 iz4 = *reinterpret_cast<const ushort4*>(&gibf[gb + EMB]);
        ushort4 in4 = *reinterpret_cast<const ushort4*>(&gibf[gb + 2*EMB]);
        ushort4 hr4 = *reinterpret_cast<const ushort4*>(&ghbf[gb]);
        ushort4 hz4 = *reinterpret_cast<const ushort4*>(&ghbf[gb + EMB]);
        ushort4 hn4 = *reinterpret_cast<const ushort4*>(&ghbf[gb + 2*EMB]);
        float4 hp4 = *reinterpret_cast<const float4*>(&hprev[hb]);
        const float ir_[4] = {bf2f(ir4.x),bf2f(ir4.y),bf2f(ir4.z),bf2f(ir4.w)};
        const float iz_[4] = {bf2f(iz4.x),bf2f(iz4.y),bf2f(iz4.z),bf2f(iz4.w)};
        const float in_[4] = {bf2f(in4.x),bf2f(in4.y),bf2f(in4.z),bf2f(in4.w)};
        const float hr_[4] = {bf2f(hr4.x),bf2f(hr4.y),bf2f(hr4.z),bf2f(hr4.w)};
        const float hz_[4] = {bf2f(hz4.x),bf2f(hz4.y),bf2f(hz4.z),bf2f(hz4.w)};
        const float hn_[4] = {bf2f(hn4.x),bf2f(hn4.y),bf2f(hn4.z),bf2f(hn4.w)};
        const float hp_[4] = {hp4.x,hp4.y,hp4.z,hp4.w};
        float hv[4], av[4];
        #pragma unroll
        for (int i = 0; i < 4; ++i) {
            float rg = sigm(ir_[i] + hr_[i]);
            float z  = sigm(iz_[i] + hz_[i]);
            float n  = tanhf(in_[i] + rg*hn_[i]);
            hv[i] = (1.f - z)*n + z*hp_[i];
            av[i] = fmaxf(hv[i], 0.f);
        }
        *reinterpret_cast<float4*>(&hout[hb])   = make_float4(hv[0],hv[1],hv[2],hv[3]);
        *reinterpret_cast<float4*>(&actout[hb]) = make_float4(av[0],av[1],av[2],av[3]);
        uint2 hp, ap;
        hp.x = (unsigned)f2bf(hv[0]) | ((unsigned)f2bf(hv[1]) << 16);
        hp.y = (unsigned)f2bf(hv[2]) | ((unsigned)f2bf(hv[3]) << 16);
        ap.x = (unsigned)f2bf(av[0]) | ((unsigned)f2bf(av[1]) << 16);
        ap.y = (unsigned)f2bf(av[2]) | ((unsigned)f2bf(av[3]) << 16);
        *reinterpret_cast<uint2*>(&hbf[hb])   = hp;
        *reinterpret_cast<uint2*>(&actbf[hb]) = ap;
    }
}

// seqsum: one vb per batch
__device__ __forceinline__ void seqsum_body(
    int b, const float* __restrict__ act, const float* __restrict__ mask,
    const float* __restrict__ saW, float* __restrict__ seqfeat,
    float* __restrict__ cmol, float* red)
{
    const int e = threadIdx.x;
    float acc = 0.f;
    for (int s = 0; s < SEQ; ++s)
        acc += act[((size_t)b*SEQ + s)*EMB + e] * mask[b*SEQ + s];
    seqfeat[b*EMB + e] = acc;
    red[e] = fmaxf(acc, 0.f) * saW[e];
    __syncthreads();
    for (int off = 128; off; off >>= 1) {
        if (e < off) red[e] += red[e + off];
        __syncthreads();
    }
    if (e == 0) cmol[b] = red[0];
}

// seqscore: 32 rows per vb
__device__ __forceinline__ void seqscore_body(
    int b2, const float* __restrict__ act, const float* __restrict__ saW,
    float* __restrict__ ad)
{
    const int lane = threadIdx.x & 63;
    const int wv   = threadIdx.x >> 6;
    const int e    = lane << 2;
    const int rb   = b2 * 32 + wv * 8;
    float4 w1 = *reinterpret_cast<const float4*>(&saW[EMB + e]);
    #pragma unroll
    for (int i = 0; i < 8; ++i) {
        const int r = rb + i;
        float4 xa = *reinterpret_cast<const float4*>(&act[(size_t)r*EMB + e]);
        float an = xa.x*w1.x + xa.y*w1.y + xa.z*w1.z + xa.w*w1.w;
        #pragma unroll
        for (int off = 32; off; off >>= 1) an += __shfl_xor(an, off, 64);
        if (lane == 0) ad[r] = an;
    }
}

// seqpv: softmax (redundant per block) + 32-row PV strip
__device__ __forceinline__ void seqpv_body(
    int st, int b, const float* __restrict__ ad, const float* __restrict__ mask,
    float saB0, const float* __restrict__ cmol, const float* __restrict__ tf,
    float* __restrict__ partial, float* w_s, float* red)
{
    const int tid = threadIdx.x;
    float mk0 = mask[b*SEQ + tid], mk1 = mask[b*SEQ + 256 + tid];
    float cb = cmol[b];
    float s0 = lrelu(cb + ad[b*SEQ + tid] + saB0)       + (mk0 == 0.f ? NEGV : 0.f);
    float s1 = lrelu(cb + ad[b*SEQ + 256 + tid] + saB0) + (mk1 == 0.f ? NEGV : 0.f);
    red[tid] = fmaxf(s0, s1); __syncthreads();
    for (int off = 128; off; off >>= 1) {
        if (tid < off) red[tid] = fmaxf(red[tid], red[tid + off]);
        __syncthreads();
    }
    float m = red[0]; __syncthreads();
    float e0 = expf(s0 - m), e1 = expf(s1 - m);
    red[tid] = e0 + e1; __syncthreads();
    for (int off = 128; off; off >>= 1) {
        if (tid < off) red[tid] += red[tid + off];
        __syncthreads();
    }
    float inv = 1.f / red[0];
    w_s[tid]       = e0 * inv * mk0;
    w_s[tid + 256] = e1 * inv * mk1;
    __syncthreads();
    float acc = 0.f;
    const int s0i = st * 32;
    #pragma unroll 4
    for (int s = s0i; s < s0i + 32; ++s)
        acc += w_s[s] * tf[((size_t)b*SEQ + s)*EMB + tid];
    partial[((size_t)b*16 + st)*EMB + tid] = acc;
}

// seqstep (256-thread version): vb = (b, quarter q), 32 vbs
template<int T0>
__device__ __forceinline__ void seqstep_body(
    int vb, const float* __restrict__ partial, const float* __restrict__ sfin,
    const ushort* __restrict__ wih, const float* __restrict__ bih,
    const ushort* __restrict__ whh, const float* __restrict__ bhh,
    float* __restrict__ sgi, float* __restrict__ sfout,
    float* __restrict__ actseq,
    float* xs, float* hs, float* gis, float* ghs)
{
    const int b = vb >> 2, q = vb & 3;
    const int tid = threadIdx.x, lane = tid & 63, wv = tid >> 6;
    {
        hs[tid] = sfin[b*EMB + tid];
        if (T0) {
            float a = 0.f;
            #pragma unroll
            for (int st = 0; st < 16; ++st)
                a += partial[((size_t)b*16 + st)*EMB + tid];
            xs[tid] = elu1(a);
        }
    }
    if (!T0) {
        for (int l = tid; l < 192; l += 256) {
            int g = (l >> 6)*EMB + (q << 6) + (l & 63);
            gis[l] = sgi[b*G3 + g];
        }
    }
    __syncthreads();
    const int nrows = T0 ? 384 : 192;
    const int rpw = nrows >> 2;               // 4 waves
    for (int i = 0; i < rpw; ++i) {
        const int l = wv * rpw + i;
        const int iswih = T0 && (l < 192);
        const int ll = (T0 && l >= 192) ? l - 192 : l;
        const int g = (ll >> 6)*EMB + (q << 6) + (ll & 63);
        const ushort* Wm = iswih ? wih : whh;
        ushort4 w4 = *reinterpret_cast<const ushort4*>(&Wm[(size_t)g*EMB + (lane << 2)]);
        float4 x4 = *reinterpret_cast<const float4*>(iswih ? &xs[lane << 2] : &hs[lane << 2]);
        float d = bf2f(w4.x)*x4.x + bf2f(w4.y)*x4.y + bf2f(w4.z)*x4.z + bf2f(w4.w)*x4.w;
        #pragma unroll
        for (int off = 32; off; off >>= 1) d += __shfl_xor(d, off, 64);
        if (lane == 0) {
            if (iswih) {
                d += bih[g];
                gis[ll] = d;
                sgi[b*G3 + g] = d;
            } else {
                ghs[ll] = d + bhh[g];
            }
        }
    }
    __syncthreads();
    if (tid < 64) {
        const int e = (q << 6) + tid;
        float rg = sigm(gis[tid]       + ghs[tid]);
        float z  = sigm(gis[64 + tid]  + ghs[64 + tid]);
        float n  = tanhf(gis[128 + tid] + rg*ghs[128 + tid]);
        float hv = (1.f - z)*n + z*hs[e];
        sfout[b*EMB + e]  = hv;
        actseq[b*EMB + e] = fmaxf(hv, 0.f);
    }
}

struct Params {
    const float *mask, *embB, *nbB, *alignW, *alignB, *attB, *gbih, *gbhh;
    const float *saW, *saB, *satB, *sgbih, *sgbhh;
    const int* idx;
    float *feat, *nbase, *h, *tf, *cdot, *ndot, *ad, *seqfeat, *sf2, *cmol, *sgi, *partial;
    ushort *aminobf, *featbf, *nbasebf, *actbf, *hbf, *ctxbf, *ntb, *gibf, *ghbf;
    ushort *embWbf, *nbWbf, *attWbf, *gwihbf, *gwhhbf, *satWbf, *sgwihbf, *sgwhhbf;
    float *act, *actseq;
};

__global__ __launch_bounds__(256, 2) void mega_kernel(Params p) {
    cg::grid_group grid = cg::this_grid();
    __shared__ MegaLds L;
    const int bid = blockIdx.x, gsz = gridDim.x;

    // P1: featnbase (BN=64), NVB=256
    for (int vb = bid; vb < 256; vb += gsz) {
        if (vb < 128)
            gemm_dev<64,1,true,true>(p.aminobf, p.embWbf, p.embB, p.feat, p.featbf,
                                     EMB, INITD, vb & 31, vb >> 5, *(GemmLdsT<64>*)&L);
        else {
            int b = vb - 128;
            gemm_dev<64,1,true,true>(p.aminobf, p.nbWbf, p.nbB, p.nbase, p.nbasebf,
                                     EMB, INITD, b & 31, b >> 5, *(GemmLdsT<64>*)&L);
        }
        __syncthreads();
    }
    grid.sync();

    for (int d = 0; d < 3; ++d) {
        const float*  center  = (d == 0) ? p.feat    : p.act;
        const float*  nbrbase = (d == 0) ? p.nbase   : p.act;
        const ushort* nbrbf   = (d == 0) ? p.nbasebf : p.actbf;
        const float*  hprev   = (d == 0) ? p.feat    : p.h;
        const ushort* hprevbf = (d == 0) ? p.featbf  : p.hbf;
        const ushort* attWd  = p.attWbf  + (size_t)d*EMB*EMB;
        const ushort* gwhhd  = p.gwhhbf  + (size_t)d*G3*EMB;
        const ushort* gwihd  = p.gwihbf  + (size_t)d*G3*EMB;
        const float*  attBd  = p.attB + d*EMB;
        const float*  gbhhd  = p.gbhh + d*G3;
        const float*  gbihd  = p.gbih + d*G3;
        const float*  alignWd = p.alignW + d*2*EMB;
        const float   alignBd = p.alignB[d];

        // P2: nt gemm (64) + gh gemm (192) + dot2 (128) = 384 vb
        for (int vb = bid; vb < 384; vb += gsz) {
            if (vb < 64)
                gemm_dev<128,0,false,true>(nbrbf, attWd, attBd, nullptr, p.ntb,
                                           EMB, EMB, vb & 31, vb >> 5, L.g);
            else if (vb < 256) {
                int b = vb - 64;
                gemm_dev<128,0,false,true>(hprevbf, gwhhd, gbhhd, nullptr, p.ghbf,
                                           G3, EMB, b & 31, b >> 5, L.g);
            } else {
                dot2_body(vb - 256, center, nbrbase, alignWd, p.cdot, p.ndot);
            }
            __syncthreads();
        }
        grid.sync();

        // P3: attn, NVB=512 (8 rows each)
        for (int vb = bid; vb < 512; vb += gsz)
            attn_body(vb, p.cdot, p.ndot, p.idx, p.ntb, alignBd, p.ctxbf);
        grid.sync();

        // P4: gi gemm, NVB=192
        for (int vb = bid; vb < 192; vb += gsz) {
            gemm_dev<128,0,false,true>(p.ctxbf, gwihd, gbihd, nullptr, p.gibf,
                                       G3, EMB, vb & 31, vb >> 5, L.g);
            __syncthreads();
        }
        grid.sync();

        // P5: gru, NVB=512 (8 rows each)
        for (int vb = bid; vb < 512; vb += gsz)
            gru_body(vb, p.gibf, p.ghbf, hprev, p.h, p.hbf, p.act, p.actbf);
        grid.sync();
    }

    // P6: tf gemm (64) + seqsum (8) + seqscore (128) = 200 vb
    for (int vb = bid; vb < 200; vb += gsz) {
        if (vb < 64)
            gemm_dev<128,0,true,false>(p.actbf, p.satWbf, p.satB, p.tf, nullptr,
                                       EMB, EMB, vb & 31, vb >> 5, L.g);
        else if (vb < 72)
            seqsum_body(vb - 64, p.act, p.mask, p.saW, p.seqfeat, p.cmol, L.red256);
        else
            seqscore_body(vb - 72, p.act, p.saW, p.ad);
        __syncthreads();
    }
    grid.sync();

    // P7: seqpv, NVB=128
    for (int vb = bid; vb < 128; vb += gsz) {
        seqpv_body(vb & 15, vb >> 4, p.ad, p.mask, p.saB[0], p.cmol, p.tf,
                   p.partial, L.pv.w_s, L.pv.red);
        __syncthreads();
    }
    grid.sync();

    // P8: seqstep T0, NVB=32
    for (int vb = bid; vb < 32; vb += gsz) {
        seqstep_body<1>(vb, p.partial, p.seqfeat, p.sgwihbf, p.sgbih,
                        p.sgwhhbf, p.sgbhh, p.sgi, p.sf2, p.actseq,
                        L.st.xs, L.st.hs, L.st.gis, L.st.ghs);
        __syncthreads();
    }
    grid.sync();

    // P9: seqstep T1, NVB=32
    for (int vb = bid; vb < 32; vb += gsz) {
        seqstep_body<0>(vb, p.partial, p.sf2, p.sgwihbf, p.sgbih,
                        p.sgwhhbf, p.sgbhh, p.sgi, p.seqfeat, p.actseq,
                        L.st.xs, L.st.hs, L.st.gis, L.st.ghs);
        __syncthreads();
    }
}

extern "C" void kernel_launch(void* const* d_in, const int* in_sizes, int n_in,
                              void* d_out, int out_size, void* d_ws, size_t ws_size,
                              hipStream_t stream) {
    (void)in_sizes; (void)n_in; (void)out_size; (void)ws_size;
    const float* amino  = (const float*)d_in[0];
    const float* mask   = (const float*)d_in[1];
    const float* embW   = (const float*)d_in[2];
    const float* embB   = (const float*)d_in[3];
    const float* nbW    = (const float*)d_in[4];
    const float* nbB    = (const float*)d_in[5];
    const float* alignW = (const float*)d_in[6];
    const float* alignB = (const float*)d_in[7];
    const float* attW   = (const float*)d_in[8];
    const float* attB   = (const float*)d_in[9];
    const float* gwih   = (const float*)d_in[10];
    const float* gwhh   = (const float*)d_in[11];
    const float* gbih   = (const float*)d_in[12];
    const float* gbhh   = (const float*)d_in[13];
    const float* saW    = (const float*)d_in[14];
    const float* saB    = (const float*)d_in[15];
    const float* satW   = (const float*)d_in[16];
    const float* satB   = (const float*)d_in[17];
    const float* sgwih  = (const float*)d_in[18];
    const float* sgbih  = (const float*)d_in[19];
    const float* sgwhh  = (const float*)d_in[20];
    const float* sgbhh  = (const float*)d_in[21];
    const int*   idx    = (const int*)d_in[22];

    char* cur = (char*)d_ws;
    auto alloc = [&](size_t bytes) -> char* {
        char* p = cur; cur += (bytes + 255) & ~(size_t)255; return p;
    };
    Params prm;
    prm.feat    = (float*)alloc((size_t)BS*EMB*4);
    prm.nbase   = (float*)alloc((size_t)BS*EMB*4);
    prm.h       = (float*)alloc((size_t)BS*EMB*4);
    prm.tf      = (float*)alloc((size_t)BS*EMB*4);
    prm.cdot    = (float*)alloc(BS*4);
    prm.ndot    = (float*)alloc(BS*4);
    prm.ad      = (float*)alloc(BS*4);
    prm.seqfeat = (float*)alloc(BSZ*EMB*4);
    prm.sf2     = (float*)alloc(BSZ*EMB*4);
    prm.cmol    = (float*)alloc(64*4);
    prm.sgi     = (float*)alloc(BSZ*G3*4);
    prm.partial = (float*)alloc((size_t)BSZ*16*EMB*4);
    prm.aminobf = (ushort*)alloc((size_t)BS*INITD*2);
    prm.featbf  = (ushort*)alloc((size_t)BS*EMB*2);
    prm.nbasebf = (ushort*)alloc((size_t)BS*EMB*2);
    prm.actbf   = (ushort*)alloc((size_t)BS*EMB*2);
    prm.hbf     = (ushort*)alloc((size_t)BS*EMB*2);
    prm.ctxbf   = (ushort*)alloc((size_t)BS*EMB*2);
    prm.ntb     = (ushort*)alloc((size_t)BS*EMB*2);
    prm.gibf    = (ushort*)alloc((size_t)BS*G3*2);
    prm.ghbf    = (ushort*)alloc((size_t)BS*G3*2);
    prm.embWbf  = (ushort*)alloc((size_t)EMB*INITD*2);
    prm.nbWbf   = (ushort*)alloc((size_t)EMB*INITD*2);
    prm.attWbf  = (ushort*)alloc((size_t)3*EMB*EMB*2);
    prm.gwihbf  = (ushort*)alloc((size_t)3*G3*EMB*2);
    prm.gwhhbf  = (ushort*)alloc((size_t)3*G3*EMB*2);
    prm.satWbf  = (ushort*)alloc((size_t)EMB*EMB*2);
    prm.sgwihbf = (ushort*)alloc((size_t)G3*EMB*2);
    prm.sgwhhbf = (ushort*)alloc((size_t)G3*EMB*2);
    prm.mask = mask; prm.embB = embB; prm.nbB = nbB; prm.alignW = alignW;
    prm.alignB = alignB; prm.attB = attB; prm.gbih = gbih; prm.gbhh = gbhh;
    prm.saW = saW; prm.saB = saB; prm.satB = satB; prm.sgbih = sgbih;
    prm.sgbhh = sgbhh; prm.idx = idx;
    prm.actseq = (float*)d_out;
    prm.act    = (float*)d_out + BSZ*EMB;

    convert9_kernel<<<dim3(1024, 9), 256, 0, stream>>>(
        amino, prm.aminobf, BS*INITD,
        embW,  prm.embWbf,  EMB*INITD,
        nbW,   prm.nbWbf,   EMB*INITD,
        attW,  prm.attWbf,  3*EMB*EMB,
        gwih,  prm.gwihbf,  3*G3*EMB,
        gwhh,  prm.gwhhbf,  3*G3*EMB,
        satW,  prm.satWbf,  EMB*EMB,
        sgwih, prm.sgwihbf, G3*EMB,
        sgwhh, prm.sgwhhbf, G3*EMB);

    int maxb = 0;
    if (hipOccupancyMaxActiveBlocksPerMultiprocessor(
            &maxb, (const void*)mega_kernel, 256, 0) != hipSuccess || maxb < 1)
        maxb = 1;
    int grid = (maxb >= 2) ? 512 : 256;
    void* args[] = { (void*)&prm };
    hipLaunchCooperativeKernel((const void*)mega_kernel, dim3(grid), dim3(256),
                               args, 0, stream);
}